// Round 1
// baseline (946.874 us; speedup 1.0000x reference)
//
#include <hip/hip_runtime.h>

#define S_LEN 2048
#define BATCH 16
#define DIM   512

typedef __bf16 bf16x8 __attribute__((ext_vector_type(8)));
typedef float  f32x4  __attribute__((ext_vector_type(4)));
typedef unsigned int u32x4 __attribute__((ext_vector_type(4)));

static __device__ __forceinline__ unsigned short f2bf(float f) {
    __bf16 h = (__bf16)f;
    return __builtin_bit_cast(unsigned short, h);
}
static __device__ __forceinline__ bf16x8 ld_bf8(const unsigned short* p) {
    u32x4 v = *reinterpret_cast<const u32x4*>(p);
    return __builtin_bit_cast(bf16x8, v);
}
static __device__ __forceinline__ f32x4 mfma16(bf16x8 a, bf16x8 b, f32x4 c) {
    return __builtin_amdgcn_mfma_f32_16x16x32_bf16(a, b, c, 0, 0, 0);
}

// ---------------- pack Wv fp32 -> bf16 [512][512] ----------------
__global__ void pack_wv(const float* __restrict__ wv, unsigned short* __restrict__ out) {
    int i = blockIdx.x * blockDim.x + threadIdx.x;   // 0..65535, 4 elems each
    float4 v = reinterpret_cast<const float4*>(wv)[i];
    uint2 r;
    r.x = (unsigned)f2bf(v.x) | ((unsigned)f2bf(v.y) << 16);
    r.y = (unsigned)f2bf(v.z) | ((unsigned)f2bf(v.w) << 16);
    reinterpret_cast<uint2*>(out)[i] = r;
}

// ---------------- pack V^T: seq [S][B][D] f32 -> vt [B][D][S] bf16 ----------------
__global__ void pack_vt(const float* __restrict__ seq, unsigned short* __restrict__ vt) {
    __shared__ float tile[32][33];
    int b  = blockIdx.z;
    int d0 = blockIdx.y * 32;
    int s0 = blockIdx.x * 32;
    int t  = threadIdx.x;
    {
        int sl = t >> 3, c4 = (t & 7) * 4;
        float4 v = *reinterpret_cast<const float4*>(
            seq + (size_t)(s0 + sl) * (BATCH * DIM) + (size_t)b * DIM + d0 + c4);
        tile[sl][c4 + 0] = v.x; tile[sl][c4 + 1] = v.y;
        tile[sl][c4 + 2] = v.z; tile[sl][c4 + 3] = v.w;
    }
    __syncthreads();
    {
        int dl = t >> 3, s4 = (t & 7) * 4;
        uint2 r;
        r.x = (unsigned)f2bf(tile[s4 + 0][dl]) | ((unsigned)f2bf(tile[s4 + 1][dl]) << 16);
        r.y = (unsigned)f2bf(tile[s4 + 2][dl]) | ((unsigned)f2bf(tile[s4 + 3][dl]) << 16);
        *reinterpret_cast<uint2*>(
            vt + (size_t)b * DIM * S_LEN + (size_t)(d0 + dl) * S_LEN + s0 + s4) = r;
    }
}

// ---------------- value = tanh(seq_in @ Wv^T + bv) -> bf16 [B*S][512] ----------------
// M=32768 (row r = b*S+s), N=512, K=512. BM=BN=BK=64, 256 thr (4 waves 2x2).
__global__ void __launch_bounds__(256) gemm_value(
        const float* __restrict__ seq, const unsigned short* __restrict__ wvb,
        const float* __restrict__ bv, unsigned short* __restrict__ val) {
    __shared__ unsigned short Asm[64][72];
    __shared__ unsigned short Bsm[64][72];
    int t  = threadIdx.x;
    int rb = blockIdx.x * 64;
    int cb = blockIdx.y * 64;
    int w = t >> 6, l = t & 63;
    int mi = w >> 1, ni = w & 1;
    int l15 = l & 15, lh = l >> 4;
    f32x4 acc[2][2] = {};

    int srow = t >> 2;            // 0..63 staging row
    int qc   = (t & 3) * 16;      // 16 elems per thread
    int gr = rb + srow;
    int sb = gr >> 11, ss = gr & 2047;
    const float* aSrc = seq + ((size_t)ss * BATCH + sb) * DIM + qc;
    const unsigned short* bSrc = wvb + (size_t)(cb + srow) * DIM + qc;

    for (int k0 = 0; k0 < DIM; k0 += 64) {
        // stage A (fp32 -> bf16)
        unsigned short ar[16];
        #pragma unroll
        for (int j = 0; j < 4; ++j) {
            float4 v = *reinterpret_cast<const float4*>(aSrc + k0 + j * 4);
            ar[j * 4 + 0] = f2bf(v.x); ar[j * 4 + 1] = f2bf(v.y);
            ar[j * 4 + 2] = f2bf(v.z); ar[j * 4 + 3] = f2bf(v.w);
        }
        *reinterpret_cast<u32x4*>(&Asm[srow][qc])     = *reinterpret_cast<u32x4*>(&ar[0]);
        *reinterpret_cast<u32x4*>(&Asm[srow][qc + 8]) = *reinterpret_cast<u32x4*>(&ar[8]);
        // stage B (already bf16)
        u32x4 b0 = *reinterpret_cast<const u32x4*>(bSrc + k0);
        u32x4 b1 = *reinterpret_cast<const u32x4*>(bSrc + k0 + 8);
        *reinterpret_cast<u32x4*>(&Bsm[srow][qc])     = b0;
        *reinterpret_cast<u32x4*>(&Bsm[srow][qc + 8]) = b1;
        __syncthreads();
        #pragma unroll
        for (int kf = 0; kf < 2; ++kf) {
            bf16x8 af[2], bfm[2];
            #pragma unroll
            for (int i = 0; i < 2; ++i)
                af[i] = ld_bf8(&Asm[mi * 32 + i * 16 + l15][kf * 32 + lh * 8]);
            #pragma unroll
            for (int j = 0; j < 2; ++j)
                bfm[j] = ld_bf8(&Bsm[ni * 32 + j * 16 + l15][kf * 32 + lh * 8]);
            #pragma unroll
            for (int i = 0; i < 2; ++i)
                #pragma unroll
                for (int j = 0; j < 2; ++j)
                    acc[i][j] = mfma16(af[i], bfm[j], acc[i][j]);
        }
        __syncthreads();
    }
    // epilogue: +bias, tanh, store bf16
    #pragma unroll
    for (int i = 0; i < 2; ++i) {
        #pragma unroll
        for (int j = 0; j < 2; ++j) {
            int gcol = cb + ni * 32 + j * 16 + l15;
            float bias = bv[gcol];
            #pragma unroll
            for (int r = 0; r < 4; ++r) {
                int grow = rb + mi * 32 + i * 16 + lh * 4 + r;
                float x = acc[i][j][r] + bias;
                val[(size_t)grow * DIM + gcol] = f2bf(tanhf(x));
            }
        }
    }
}

// ---------------- fused flash attention ----------------
// Q=K=val [B][S][512] bf16, V^T=vt [B][512][S] bf16, out [S][B][512] f32.
// Block: 512 thr (8 waves). QBLK=32, KVBLK=64. Wave w: QK frag (mi=w>>2, ni=w&3);
// PV d-slice = w*64. Q frags in registers; K/V frags direct from global (L2).
__global__ void __launch_bounds__(512) attn_fused(
        const unsigned short* __restrict__ val, const unsigned short* __restrict__ vt,
        float* __restrict__ out) {
    __shared__ float Sbuf[32][68];
    __shared__ unsigned short Pbuf[32][72];
    __shared__ float stats_m[32], stats_l[32], scalebuf[32];

    int t = threadIdx.x;
    int w = t >> 6, l = t & 63;
    int l15 = l & 15, lh = l >> 4;
    int qb = blockIdx.x * 32;
    int b  = blockIdx.y;
    int mi = w >> 2, ni = w & 3;
    int wd = w;                       // d-slice index (64 cols each)

    if (t < 32) { stats_m[t] = -1e30f; stats_l[t] = 0.0f; }

    // Q fragments in registers: rows qb + mi*16 + l15, full K=512
    bf16x8 qf[16];
    {
        const unsigned short* qrow =
            val + ((size_t)b * S_LEN + qb + mi * 16 + l15) * DIM + lh * 8;
        #pragma unroll
        for (int kf = 0; kf < 16; ++kf) qf[kf] = ld_bf8(qrow + kf * 32);
    }
    f32x4 o[2][4] = {};
    const unsigned short* kbase = val + (size_t)b * S_LEN * DIM;
    const unsigned short* vbase = vt + (size_t)b * DIM * S_LEN;
    __syncthreads();

    for (int kt = 0; kt < S_LEN / 64; ++kt) {
        int kv0 = kt * 64;
        // ---- QK^T: this wave's 16x16 frag over K=512 ----
        f32x4 acc = {};
        const unsigned short* krow =
            kbase + (size_t)(kv0 + ni * 16 + l15) * DIM + lh * 8;
        #pragma unroll
        for (int kf = 0; kf < 16; ++kf) {
            bf16x8 kfr = ld_bf8(krow + kf * 32);
            acc = mfma16(qf[kf], kfr, acc);
        }
        #pragma unroll
        for (int r = 0; r < 4; ++r)
            Sbuf[mi * 16 + lh * 4 + r][ni * 16 + l15] = acc[r];
        __syncthreads();

        // ---- online softmax (32 rows x 16 thr each) ----
        {
            int row = t >> 4, c0 = (t & 15) * 4;
            float4 sv = *reinterpret_cast<const float4*>(&Sbuf[row][c0]);
            float mt = fmaxf(fmaxf(sv.x, sv.y), fmaxf(sv.z, sv.w));
            #pragma unroll
            for (int m = 1; m <= 8; m <<= 1) mt = fmaxf(mt, __shfl_xor(mt, m, 64));
            float m_old = stats_m[row], l_old = stats_l[row];
            float m_new = fmaxf(m_old, mt);
            float p0 = __expf(sv.x - m_new), p1 = __expf(sv.y - m_new);
            float p2 = __expf(sv.z - m_new), p3 = __expf(sv.w - m_new);
            float lt = (p0 + p1) + (p2 + p3);
            #pragma unroll
            for (int m = 1; m <= 8; m <<= 1) lt += __shfl_xor(lt, m, 64);
            uint2 pk;
            pk.x = (unsigned)f2bf(p0) | ((unsigned)f2bf(p1) << 16);
            pk.y = (unsigned)f2bf(p2) | ((unsigned)f2bf(p3) << 16);
            *reinterpret_cast<uint2*>(&Pbuf[row][c0]) = pk;
            if ((t & 15) == 0) {
                float alpha = __expf(m_old - m_new);
                stats_m[row] = m_new;
                stats_l[row] = l_old * alpha + lt;
                scalebuf[row] = alpha;
            }
        }
        __syncthreads();

        // ---- rescale O ----
        #pragma unroll
        for (int mo = 0; mo < 2; ++mo) {
            #pragma unroll
            for (int r = 0; r < 4; ++r) {
                float a = scalebuf[mo * 16 + lh * 4 + r];
                #pragma unroll
                for (int nd = 0; nd < 4; ++nd) o[mo][nd][r] *= a;
            }
        }
        // ---- PV: O += P @ V ----
        #pragma unroll
        for (int kf2 = 0; kf2 < 2; ++kf2) {
            bf16x8 pa0 = ld_bf8(&Pbuf[l15][kf2 * 32 + lh * 8]);
            bf16x8 pa1 = ld_bf8(&Pbuf[16 + l15][kf2 * 32 + lh * 8]);
            #pragma unroll
            for (int nd = 0; nd < 4; ++nd) {
                const unsigned short* vrow =
                    vbase + (size_t)(wd * 64 + nd * 16 + l15) * S_LEN + kv0 + kf2 * 32 + lh * 8;
                bf16x8 vb = ld_bf8(vrow);
                o[0][nd] = mfma16(pa0, vb, o[0][nd]);
                o[1][nd] = mfma16(pa1, vb, o[1][nd]);
            }
        }
    }

    // ---- epilogue: /l, store fp32 to out[S][B][D] ----
    #pragma unroll
    for (int mo = 0; mo < 2; ++mo) {
        #pragma unroll
        for (int r = 0; r < 4; ++r) {
            int q = mo * 16 + lh * 4 + r;
            float linv = 1.0f / stats_l[q];
            #pragma unroll
            for (int nd = 0; nd < 4; ++nd) {
                out[(size_t)(qb + q) * (BATCH * DIM) + (size_t)b * DIM
                    + wd * 64 + nd * 16 + l15] = o[mo][nd][r] * linv;
            }
        }
    }
}

extern "C" void kernel_launch(void* const* d_in, const int* in_sizes, int n_in,
                              void* d_out, int out_size, void* d_ws, size_t ws_size,
                              hipStream_t stream) {
    const float* seq = (const float*)d_in[0];   // [S][B][D] f32
    const float* wv  = (const float*)d_in[1];   // [D][D] f32
    const float* bv  = (const float*)d_in[2];   // [D] f32
    float* outp = (float*)d_out;                // [S][B][D] f32

    unsigned short* wsVal = (unsigned short*)d_ws;                          // 32 MB
    unsigned short* wsVt  = (unsigned short*)((char*)d_ws + 33554432);      // 32 MB
    unsigned short* wsWv  = (unsigned short*)((char*)d_ws + 67108864);      // 0.5 MB

    pack_wv<<<dim3(DIM * DIM / 4 / 256), dim3(256), 0, stream>>>(wv, wsWv);
    pack_vt<<<dim3(S_LEN / 32, DIM / 32, BATCH), dim3(256), 0, stream>>>(seq, wsVt);
    gemm_value<<<dim3(BATCH * S_LEN / 64, DIM / 64), dim3(256), 0, stream>>>(
        seq, wsWv, bv, wsVal);
    attn_fused<<<dim3(S_LEN / 32, BATCH), dim3(512), 0, stream>>>(wsVal, wsVt, outp);
}

// Round 2
// 383.073 us; speedup vs baseline: 2.4718x; 2.4718x over previous
//
#include <hip/hip_runtime.h>

#define S_LEN 2048
#define BATCH 16
#define DIM   512
#define KVB   32
#define QB    64

typedef __bf16 bf16x8 __attribute__((ext_vector_type(8)));
typedef float  f32x4  __attribute__((ext_vector_type(4)));
typedef unsigned int u32x4 __attribute__((ext_vector_type(4)));

static __device__ __forceinline__ unsigned short f2bf(float f) {
    __bf16 h = (__bf16)f;
    return __builtin_bit_cast(unsigned short, h);
}
static __device__ __forceinline__ bf16x8 ld_bf8(const unsigned short* p) {
    u32x4 v = *reinterpret_cast<const u32x4*>(p);
    return __builtin_bit_cast(bf16x8, v);
}
static __device__ __forceinline__ f32x4 mfma16(bf16x8 a, bf16x8 b, f32x4 c) {
    return __builtin_amdgcn_mfma_f32_16x16x32_bf16(a, b, c, 0, 0, 0);
}
static __device__ __forceinline__ void gload16(const unsigned short* g, unsigned short* l) {
    __builtin_amdgcn_global_load_lds(
        (const __attribute__((address_space(1))) unsigned int*)g,
        (__attribute__((address_space(3))) unsigned int*)l, 16, 0, 0);
}

// ---------------- pack Wv fp32 -> bf16 [512][512] ----------------
__global__ void pack_wv(const float* __restrict__ wv, unsigned short* __restrict__ out) {
    int i = blockIdx.x * blockDim.x + threadIdx.x;
    float4 v = reinterpret_cast<const float4*>(wv)[i];
    uint2 r;
    r.x = (unsigned)f2bf(v.x) | ((unsigned)f2bf(v.y) << 16);
    r.y = (unsigned)f2bf(v.z) | ((unsigned)f2bf(v.w) << 16);
    reinterpret_cast<uint2*>(out)[i] = r;
}

// ---------------- pack V^T: seq [S][B][D] f32 -> vt [B][D][S] bf16 ----------------
__global__ void pack_vt(const float* __restrict__ seq, unsigned short* __restrict__ vt) {
    __shared__ float tile[32][33];
    int b  = blockIdx.z;
    int d0 = blockIdx.y * 32;
    int s0 = blockIdx.x * 32;
    int t  = threadIdx.x;
    {
        int sl = t >> 3, c4 = (t & 7) * 4;
        float4 v = *reinterpret_cast<const float4*>(
            seq + (size_t)(s0 + sl) * (BATCH * DIM) + (size_t)b * DIM + d0 + c4);
        tile[sl][c4 + 0] = v.x; tile[sl][c4 + 1] = v.y;
        tile[sl][c4 + 2] = v.z; tile[sl][c4 + 3] = v.w;
    }
    __syncthreads();
    {
        int dl = t >> 3, s4 = (t & 7) * 4;
        uint2 r;
        r.x = (unsigned)f2bf(tile[s4 + 0][dl]) | ((unsigned)f2bf(tile[s4 + 1][dl]) << 16);
        r.y = (unsigned)f2bf(tile[s4 + 2][dl]) | ((unsigned)f2bf(tile[s4 + 3][dl]) << 16);
        *reinterpret_cast<uint2*>(
            vt + (size_t)b * DIM * S_LEN + (size_t)(d0 + dl) * S_LEN + s0 + s4) = r;
    }
}

// ---------------- value = tanh(seq_in @ Wv^T + bv) -> bf16 [B*S][512] ----------------
__global__ void __launch_bounds__(256) gemm_value(
        const float* __restrict__ seq, const unsigned short* __restrict__ wvb,
        const float* __restrict__ bv, unsigned short* __restrict__ val) {
    __shared__ unsigned short Asm[64][72];
    __shared__ unsigned short Bsm[64][72];
    int t  = threadIdx.x;
    int rb = blockIdx.x * 64;
    int cb = blockIdx.y * 64;
    int w = t >> 6, l = t & 63;
    int mi = w >> 1, ni = w & 1;
    int l15 = l & 15, lh = l >> 4;
    f32x4 acc[2][2] = {};

    int srow = t >> 2;
    int qc   = (t & 3) * 16;
    int gr = rb + srow;
    int sb = gr >> 11, ss = gr & 2047;
    const float* aSrc = seq + ((size_t)ss * BATCH + sb) * DIM + qc;
    const unsigned short* bSrc = wvb + (size_t)(cb + srow) * DIM + qc;

    for (int k0 = 0; k0 < DIM; k0 += 64) {
        unsigned short ar[16];
        #pragma unroll
        for (int j = 0; j < 4; ++j) {
            float4 v = *reinterpret_cast<const float4*>(aSrc + k0 + j * 4);
            ar[j * 4 + 0] = f2bf(v.x); ar[j * 4 + 1] = f2bf(v.y);
            ar[j * 4 + 2] = f2bf(v.z); ar[j * 4 + 3] = f2bf(v.w);
        }
        *reinterpret_cast<u32x4*>(&Asm[srow][qc])     = *reinterpret_cast<u32x4*>(&ar[0]);
        *reinterpret_cast<u32x4*>(&Asm[srow][qc + 8]) = *reinterpret_cast<u32x4*>(&ar[8]);
        u32x4 b0 = *reinterpret_cast<const u32x4*>(bSrc + k0);
        u32x4 b1 = *reinterpret_cast<const u32x4*>(bSrc + k0 + 8);
        *reinterpret_cast<u32x4*>(&Bsm[srow][qc])     = b0;
        *reinterpret_cast<u32x4*>(&Bsm[srow][qc + 8]) = b1;
        __syncthreads();
        #pragma unroll
        for (int kf = 0; kf < 2; ++kf) {
            bf16x8 af[2], bfm[2];
            #pragma unroll
            for (int i = 0; i < 2; ++i)
                af[i] = ld_bf8(&Asm[mi * 32 + i * 16 + l15][kf * 32 + lh * 8]);
            #pragma unroll
            for (int j = 0; j < 2; ++j)
                bfm[j] = ld_bf8(&Bsm[ni * 32 + j * 16 + l15][kf * 32 + lh * 8]);
            #pragma unroll
            for (int i = 0; i < 2; ++i)
                #pragma unroll
                for (int j = 0; j < 2; ++j)
                    acc[i][j] = mfma16(af[i], bfm[j], acc[i][j]);
        }
        __syncthreads();
    }
    #pragma unroll
    for (int i = 0; i < 2; ++i) {
        #pragma unroll
        for (int j = 0; j < 2; ++j) {
            int gcol = cb + ni * 32 + j * 16 + l15;
            float bias = bv[gcol];
            #pragma unroll
            for (int r = 0; r < 4; ++r) {
                int grow = rb + mi * 32 + i * 16 + lh * 4 + r;
                float x = acc[i][j][r] + bias;
                val[(size_t)grow * DIM + gcol] = f2bf(tanhf(x));
            }
        }
    }
}

// ---------------- fused flash attention v2 ----------------
// QBLK=64, KVBLK=32, 8 waves. K,V double-buffered in LDS via global_load_lds.
// QK: wave (qi=w&3, ki=w>>2) -> S[qi*16..+16][ki*16..+16], K=512.
// PV: wave (qi=w&3, di=w>>2) -> O[qi*16..+16][di*256..+256].
// K-tile XOR-swizzled (short_off ^= (row&7)*8) via pre-swizzled global source.
__global__ void __launch_bounds__(512, 2) attn_fused(
        const unsigned short* __restrict__ val, const unsigned short* __restrict__ vt,
        float* __restrict__ out) {
    extern __shared__ char smem[];
    unsigned short* Kt = (unsigned short*)smem;              // [2][32][512] 64KB
    unsigned short* Vt = (unsigned short*)(smem + 65536);    // [2][512][32] 64KB
    float*          Sb = (float*)(smem + 131072);            // [64][36]
    unsigned short* Pb = (unsigned short*)(smem + 140288);   // [64][48]
    float*          st_m = (float*)(smem + 146432);          // [64]
    float*          st_l = st_m + 64;
    float*          st_s = st_m + 128;

    int t = threadIdx.x;
    int w = t >> 6, l = t & 63;
    int l15 = l & 15, lh = l >> 4;

    // bijective XCD-chunked swizzle: 512 blocks, 8 XCDs, 64/XCD (2 batches each)
    int wg  = blockIdx.x;
    int swz = (wg & 7) * 64 + (wg >> 3);
    int b   = swz >> 5;
    int qb  = (swz & 31) * QB;
    int qi = w & 3, khi = w >> 2, di = w >> 2;

    const unsigned short* valb = val + (size_t)b * S_LEN * DIM;
    const unsigned short* vtb  = vt  + (size_t)b * DIM * S_LEN;

    if (t < 64) { st_m[t] = -1e30f; st_l[t] = 0.0f; }

    // Q fragments: rows qb + qi*16 + l15, full K=512 (64 VGPR)
    bf16x8 qf[16];
    {
        const unsigned short* qrow = valb + (size_t)(qb + qi * 16 + l15) * DIM + lh * 8;
        #pragma unroll
        for (int kf = 0; kf < 16; ++kf) qf[kf] = ld_bf8(qrow + kf * 32);
    }
    f32x4 o[16] = {};   // 16 d-chunks x 4 rows (64 regs)

    // ---- staging: K tile [32][512] (swizzled source), V tile [512][32] linear ----
    auto stage = [&](int buf, int kv0) {
        unsigned short* kb = Kt + buf * 16384;
        unsigned short* vb = Vt + buf * 16384;
        #pragma unroll
        for (int i = 0; i < 4; ++i) {
            int row = i * 8 + w;
            gload16(valb + (size_t)(kv0 + row) * DIM + ((l ^ w) * 8), kb + row * 512);
        }
        #pragma unroll
        for (int i = 0; i < 4; ++i) {
            int d = i * 128 + w * 16 + (l >> 2);
            gload16(vtb + (size_t)d * S_LEN + kv0 + (l & 3) * 8, vb + i * 4096 + w * 512);
        }
    };

    stage(0, 0);
    __syncthreads();   // drains staging vmcnt + barrier

    int cur = 0;
    for (int kt = 0; kt < S_LEN / KVB; ++kt) {
        if (kt + 1 < S_LEN / KVB) stage(cur ^ 1, (kt + 1) * KVB);

        // ---- QK^T from swizzled K tile ----
        {
            const unsigned short* kb = Kt + cur * 16384 + (khi * 16 + l15) * 512;
            int sw = (l15 & 7) << 3;
            f32x4 a0 = {}, a1 = {};
            #pragma unroll
            for (int kf = 0; kf < 16; kf += 2) {
                bf16x8 k0 = ld_bf8(kb + ((kf * 32 + lh * 8) ^ sw));
                bf16x8 k1 = ld_bf8(kb + (((kf + 1) * 32 + lh * 8) ^ sw));
                a0 = mfma16(qf[kf], k0, a0);
                a1 = mfma16(qf[kf + 1], k1, a1);
            }
            #pragma unroll
            for (int r = 0; r < 4; ++r)
                Sb[(qi * 16 + lh * 4 + r) * 36 + khi * 16 + l15] = a0[r] + a1[r];
        }
        asm volatile("s_waitcnt lgkmcnt(0)" ::: "memory");
        __builtin_amdgcn_s_barrier();

        // ---- online softmax: 64 rows x 8 threads ----
        {
            int row = t >> 3, c0 = (t & 7) * 4;
            float4 sv = *reinterpret_cast<const float4*>(&Sb[row * 36 + c0]);
            float mt = fmaxf(fmaxf(sv.x, sv.y), fmaxf(sv.z, sv.w));
            #pragma unroll
            for (int m = 1; m <= 4; m <<= 1) mt = fmaxf(mt, __shfl_xor(mt, m, 64));
            float m_old = st_m[row];
            float m_new = fmaxf(m_old, mt);
            float p0 = __expf(sv.x - m_new), p1 = __expf(sv.y - m_new);
            float p2 = __expf(sv.z - m_new), p3 = __expf(sv.w - m_new);
            float lt = (p0 + p1) + (p2 + p3);
            #pragma unroll
            for (int m = 1; m <= 4; m <<= 1) lt += __shfl_xor(lt, m, 64);
            uint2 pk;
            pk.x = (unsigned)f2bf(p0) | ((unsigned)f2bf(p1) << 16);
            pk.y = (unsigned)f2bf(p2) | ((unsigned)f2bf(p3) << 16);
            *reinterpret_cast<uint2*>(&Pb[row * 48 + c0]) = pk;
            if ((t & 7) == 0) {
                float alpha = __expf(m_old - m_new);
                st_s[row] = alpha;
                st_m[row] = m_new;
                st_l[row] = st_l[row] * alpha + lt;
            }
        }
        asm volatile("s_waitcnt lgkmcnt(0)" ::: "memory");
        __builtin_amdgcn_s_barrier();

        // ---- rescale O, then PV ----
        {
            float sc[4];
            #pragma unroll
            for (int r = 0; r < 4; ++r) sc[r] = st_s[qi * 16 + lh * 4 + r];
            #pragma unroll
            for (int nd = 0; nd < 16; ++nd)
                #pragma unroll
                for (int r = 0; r < 4; ++r) o[nd][r] *= sc[r];

            bf16x8 pa = ld_bf8(Pb + (qi * 16 + l15) * 48 + lh * 8);
            const unsigned short* vb = Vt + cur * 16384;
            #pragma unroll
            for (int nd = 0; nd < 16; ++nd) {
                bf16x8 vv = ld_bf8(vb + (di * 256 + nd * 16 + l15) * 32 + lh * 8);
                o[nd] = mfma16(pa, vv, o[nd]);
            }
        }
        __syncthreads();   // drains staging vmcnt; safe dbuf swap
        cur ^= 1;
    }

    // ---- epilogue ----
    float linv[4];
    #pragma unroll
    for (int r = 0; r < 4; ++r) linv[r] = 1.0f / st_l[qi * 16 + lh * 4 + r];
    #pragma unroll
    for (int nd = 0; nd < 16; ++nd) {
        int col = di * 256 + nd * 16 + l15;
        #pragma unroll
        for (int r = 0; r < 4; ++r) {
            int row = qb + qi * 16 + lh * 4 + r;
            out[(size_t)row * (BATCH * DIM) + (size_t)b * DIM + col] = o[nd][r] * linv[r];
        }
    }
}

extern "C" void kernel_launch(void* const* d_in, const int* in_sizes, int n_in,
                              void* d_out, int out_size, void* d_ws, size_t ws_size,
                              hipStream_t stream) {
    const float* seq = (const float*)d_in[0];   // [S][B][D] f32
    const float* wv  = (const float*)d_in[1];   // [D][D] f32
    const float* bv  = (const float*)d_in[2];   // [D] f32
    float* outp = (float*)d_out;                // [S][B][D] f32

    unsigned short* wsVal = (unsigned short*)d_ws;                          // 32 MB
    unsigned short* wsVt  = (unsigned short*)((char*)d_ws + 33554432);      // 32 MB
    unsigned short* wsWv  = (unsigned short*)((char*)d_ws + 67108864);      // 0.5 MB

    pack_wv<<<dim3(DIM * DIM / 4 / 256), dim3(256), 0, stream>>>(wv, wsWv);
    pack_vt<<<dim3(S_LEN / 32, DIM / 32, BATCH), dim3(256), 0, stream>>>(seq, wsVt);
    gemm_value<<<dim3(BATCH * S_LEN / 64, DIM / 64), dim3(256), 0, stream>>>(
        seq, wsWv, bv, wsVal);
    attn_fused<<<dim3(512), dim3(512), 147200, stream>>>(wsVal, wsVt, outp);
}